// Round 10
// baseline (61.862 us; speedup 1.0000x reference)
//
#include <hip/hip_runtime.h>
#include <math.h>

typedef _Float16 f16x8 __attribute__((ext_vector_type(8)));
typedef float f32x16 __attribute__((ext_vector_type(16)));

#define TILE 1024  // refs per LDS stage: 1024 * 32B = 32 KB

__device__ __forceinline__ float decode_scalar(const int* p) {
    int i = *p;
    if (i > -16777216 && i < 16777216) return (float)i;
    return __int_as_float(i);
}
__device__ __forceinline__ float min3f(float a, float b, float c) {
    float d;
    asm("v_min3_f32 %0, %1, %2, %3" : "=v"(d) : "v"(a), "v"(b), "v"(c));
    return d;
}
#define PIN16(x) asm("" : "+v"(x))

// K=16 encoding, a = -2*pt, hi/lo f16 split, rn = |pt|^2:
//  A (query): [ah3, al3, ah3, al3, qnh, qnl, 1, 1]   (half 0 = k0-7, half 1 = k8-15)
//  B (ref)  : [bh3, bh3, bl3, bl3, 1, 1, rnh, rnl]
//  sum_k A_k B_k = (ah+al)·(bh+bl) + qn + rn = ||q-r||^2 (exact to ~fp32)
__device__ __forceinline__ f16x8 make_afrag(float x, float y, float z, int half) {
    const float rn = fmaf(x, x, fmaf(y, y, z * z));
    const float ax = -2.f * x, ay = -2.f * y, az = -2.f * z;
    const _Float16 ahx = (_Float16)ax, ahy = (_Float16)ay, ahz = (_Float16)az;
    const _Float16 alx = (_Float16)(ax - (float)ahx);
    const _Float16 aly = (_Float16)(ay - (float)ahy);
    const _Float16 alz = (_Float16)(az - (float)ahz);
    const _Float16 rh = (_Float16)rn, rl = (_Float16)(rn - (float)rh);
    const _Float16 one = (_Float16)1.f;
    if (half == 0) return (f16x8){ahx, ahy, ahz, alx, aly, alz, ahx, ahy};
    return (f16x8){ahz, alx, aly, alz, rh, rl, one, one};
}
__device__ __forceinline__ void make_bfrags(float x, float y, float z,
                                            f16x8* b0, f16x8* b1) {
    const float rn = fmaf(x, x, fmaf(y, y, z * z));
    const _Float16 bhx = (_Float16)x, bhy = (_Float16)y, bhz = (_Float16)z;
    const _Float16 blx = (_Float16)(x - (float)bhx);
    const _Float16 bly = (_Float16)(y - (float)bhy);
    const _Float16 blz = (_Float16)(z - (float)bhz);
    const _Float16 rh = (_Float16)rn, rl = (_Float16)(rn - (float)rh);
    const _Float16 one = (_Float16)1.f;
    *b0 = (f16x8){bhx, bhy, bhz, bhx, bhy, bhz, blx, bly};
    *b1 = (f16x8){blz, blx, bly, blz, one, one, rh, rl};
}

// Stage 1 (fused pack): 32x32x16 MFMA distance tiles, running column-min.
// LDS layout: group g = ref>>5 (32 refs, 1024B); within group: half0 frags of
// refs 0..31, then half1 frags. A wave's read (idx = 2tp*64 + lane) is a
// CONTIGUOUS 1024B block -> zero bank conflicts (was stride-32B, 8-way).
__global__ __launch_bounds__(256) void nn_mfma(
    const float* __restrict__ preds, const float* __restrict__ gts,
    int M, int N, int B, int rsplit, int Qstride, float* __restrict__ part)
{
    const int zc    = blockIdx.z;
    const int dir   = zc / rsplit;       // 0: q=preds ref=gts ; 1: q=gts ref=preds
    const int chunk = zc - dir * rsplit;
    const int b     = blockIdx.y;

    const int Q = dir ? N : M;
    const int R = dir ? M : N;
    const float* __restrict__ qraw = (dir ? gts : preds) + (size_t)b * Q * 3;
    const float* __restrict__ rraw = (dir ? preds : gts) + (size_t)b * R * 3;

    const int q0blk = blockIdx.x * 256;
    if (q0blk >= Q) return;
    const int tid  = threadIdx.x;
    const int lane = tid & 63, w = tid >> 6;
    const int q0   = q0blk + w * 64;            // wave owns queries q0..q0+63
    const int lrow = lane & 31, lh = lane >> 5; // A row / k-half

    float ax = 0.f, ay = 0.f, az = 0.f, bx = 0.f, by = 0.f, bz = 0.f;
    const int qa = q0 + lrow, qb = q0 + 32 + lrow;
    if (qa < Q) { const float* s = qraw + (size_t)qa * 3; ax = s[0]; ay = s[1]; az = s[2]; }
    if (qb < Q) { const float* s = qraw + (size_t)qb * 3; bx = s[0]; by = s[1]; bz = s[2]; }
    const f16x8 af0 = make_afrag(ax, ay, az, lh);
    const f16x8 af1 = make_afrag(bx, by, bz, lh);

    __shared__ f16x8 sB[TILE * 2];

    f32x16 z16 = {0.f,0.f,0.f,0.f, 0.f,0.f,0.f,0.f,
                  0.f,0.f,0.f,0.f, 0.f,0.f,0.f,0.f};
    PIN16(z16);                 // keep the zero C-tile in arch VGPRs
    f32x16 rm0, rm1;
    #pragma unroll
    for (int j = 0; j < 16; ++j) { rm0[j] = INFINITY; rm1[j] = INFINITY; }
    PIN16(rm0); PIN16(rm1);

    const int tilesTotal = (R + TILE - 1) / TILE;
    const int tpc = (tilesTotal + rsplit - 1) / rsplit;
    const int t0 = chunk * tpc;
    const int t1 = min(tilesTotal, t0 + tpc);

    for (int tt = t0; tt < t1; ++tt) {
        const int s0 = tt * TILE;
        __syncthreads();
        #pragma unroll
        for (int k = 0; k < 4; ++k) {
            const int p  = tid + k * 256;
            const int gi = s0 + p;
            f16x8 b0, b1;
            if (gi < R) {
                const float* s = rraw + (size_t)gi * 3;
                make_bfrags(s[0], s[1], s[2], &b0, &b1);
            } else {
                const _Float16 z0 = (_Float16)0.f, one = (_Float16)1.f;
                const _Float16 big = (_Float16)60000.f;   // pad -> huge dist (finite)
                b0 = (f16x8){z0, z0, z0, z0, z0, z0, z0, z0};
                b1 = (f16x8){z0, z0, z0, z0, one, one, big, z0};
            }
            const int g = p >> 5, sl = p & 31;
            sB[g * 64 + sl]      = b0;
            sB[g * 64 + 32 + sl] = b1;
        }
        __syncthreads();

        // lane reads slot (2tp*64 + lane): contiguous 1KB per wave read
        f16x8 nb0 = sB[lane];
        f16x8 nb1 = sB[64 + lane];
        #pragma unroll 1
        for (int tp = 0; tp < TILE / 64; ++tp) {
            const f16x8 cb0 = nb0, cb1 = nb1;
            if (tp < TILE / 64 - 1) {   // uniform prefetch of next 64-ref pair
                nb0 = sB[(2 * tp + 2) * 64 + lane];
                nb1 = sB[(2 * tp + 3) * 64 + lane];
            }
            f32x16 d00 = __builtin_amdgcn_mfma_f32_32x32x16_f16(af0, cb0, z16, 0, 0, 0);
            PIN16(d00);
            f32x16 d01 = __builtin_amdgcn_mfma_f32_32x32x16_f16(af0, cb1, z16, 0, 0, 0);
            PIN16(d01);
            #pragma unroll
            for (int j = 0; j < 16; ++j) rm0[j] = min3f(d00[j], d01[j], rm0[j]);
            f32x16 d10 = __builtin_amdgcn_mfma_f32_32x32x16_f16(af1, cb0, z16, 0, 0, 0);
            PIN16(d10);
            f32x16 d11 = __builtin_amdgcn_mfma_f32_32x32x16_f16(af1, cb1, z16, 0, 0, 0);
            PIN16(d11);
            #pragma unroll
            for (int j = 0; j < 16; ++j) rm1[j] = min3f(d10[j], d11[j], rm1[j]);
        }
    }

    // reduce over the 32 ref-columns (xor bits 0-4 stay within the lh group)
    #pragma unroll
    for (int m2 = 1; m2 <= 16; m2 <<= 1) {
        #pragma unroll
        for (int j = 0; j < 16; ++j) {
            rm0[j] = fminf(rm0[j], __shfl_xor(rm0[j], m2, 64));
            rm1[j] = fminf(rm1[j], __shfl_xor(rm1[j], m2, 64));
        }
    }

    // lanes 0 and 32 hold complementary row sets: row = (j&3)+8*(j>>2)+4*lh
    if ((lane & 31) == 0) {
        const size_t pbase = (((size_t)dir * B + b) * rsplit + chunk) * (size_t)Qstride + q0;
        #pragma unroll
        for (int j = 0; j < 16; ++j) {
            const int row = (j & 3) + 8 * (j >> 2) + 4 * lh;
            part[pbase + row]      = rm0[j];
            part[pbase + 32 + row] = rm1[j];
        }
    }
}

// Stage 2: combine rsplit partial mins, Huber, wave reduce, atomicAdd.
__global__ __launch_bounds__(256) void huber_reduce(
    const float* __restrict__ part, const int* __restrict__ cptr,
    int M, int N, int B, int rsplit, int Qstride, float* __restrict__ out)
{
    const int dir = blockIdx.z;
    const int b   = blockIdx.y;
    const int Q   = dir ? N : M;
    const int j   = blockIdx.x * blockDim.x + threadIdx.x;

    float h = 0.f;
    if (j < Q) {
        const size_t base = (((size_t)dir * B + b) * rsplit) * (size_t)Qstride + j;
        float v = part[base];
        #pragma unroll 4
        for (int k = 1; k < rsplit; ++k) v = fminf(v, part[base + (size_t)k * Qstride]);
        const float c = decode_scalar(cptr);
        h = (v < c) ? (0.5f * v * v) : fmaf(c, v, -0.5f * c * c);
    }

    #pragma unroll
    for (int off = 32; off > 0; off >>= 1) h += __shfl_down(h, off, 64);
    if ((threadIdx.x & 63) == 0) atomicAdd(out, h);
}

extern "C" void kernel_launch(void* const* d_in, const int* in_sizes, int n_in,
                              void* d_out, int out_size, void* d_ws, size_t ws_size,
                              hipStream_t stream) {
    const float* preds = (const float*)d_in[0];
    const float* gts   = (const float*)d_in[1];
    const int*   cptr  = (const int*)d_in[2];

    const int B = 4, D = 3;
    const int M = in_sizes[0] / (B * D);
    const int N = in_sizes[1] / (B * D);
    const int Qmax = (M > N) ? M : N;
    const int Qstride = (Qmax + 255) & ~255;
    const int rsplit = 4;

    float* part = (float*)d_ws;   // 2*B*rsplit*Qstride floats (1 MB @ 8192)
    hipMemsetAsync(d_out, 0, (size_t)out_size * sizeof(float), stream);

    dim3 g1(Qstride / 256, B, 2 * rsplit);
    nn_mfma<<<g1, 256, 0, stream>>>(preds, gts, M, N, B, rsplit, Qstride, part);

    dim3 g2((Qmax + 255) / 256, B, 2);
    huber_reduce<<<g2, 256, 0, stream>>>(part, cptr, M, N, B, rsplit, Qstride,
                                         (float*)d_out);
}

// Round 11
// 54.835 us; speedup vs baseline: 1.1281x; 1.1281x over previous
//
#include <hip/hip_runtime.h>
#include <math.h>

typedef _Float16 f16x8 __attribute__((ext_vector_type(8)));
typedef float f32x16 __attribute__((ext_vector_type(16)));

#define TILE 1024  // refs per LDS stage: 1024 * 32B = 32 KB

__device__ __forceinline__ float decode_scalar(const int* p) {
    int i = *p;
    if (i > -16777216 && i < 16777216) return (float)i;
    return __int_as_float(i);
}
__device__ __forceinline__ float min3f(float a, float b, float c) {
    float d;
    asm("v_min3_f32 %0, %1, %2, %3" : "=v"(d) : "v"(a), "v"(b), "v"(c));
    return d;
}

// K=16 encoding, a = -2*pt, hi/lo f16 split, rn = |pt|^2:
//  A (query): [ah3, al3, ah3, al3, qnh, qnl, 1, 1]   (half 0 = k0-7, half 1 = k8-15)
//  B (ref)  : [bh3, bh3, bl3, bl3, 1, 1, rnh, rnl]
//  sum_k A_k B_k = (ah+al)·(bh+bl) + qn + rn = ||q-r||^2 (exact to ~fp32)
__device__ __forceinline__ f16x8 make_afrag(float x, float y, float z, int half) {
    const float rn = fmaf(x, x, fmaf(y, y, z * z));
    const float ax = -2.f * x, ay = -2.f * y, az = -2.f * z;
    const _Float16 ahx = (_Float16)ax, ahy = (_Float16)ay, ahz = (_Float16)az;
    const _Float16 alx = (_Float16)(ax - (float)ahx);
    const _Float16 aly = (_Float16)(ay - (float)ahy);
    const _Float16 alz = (_Float16)(az - (float)ahz);
    const _Float16 rh = (_Float16)rn, rl = (_Float16)(rn - (float)rh);
    const _Float16 one = (_Float16)1.f;
    if (half == 0) return (f16x8){ahx, ahy, ahz, alx, aly, alz, ahx, ahy};
    return (f16x8){ahz, alx, aly, alz, rh, rl, one, one};
}
__device__ __forceinline__ void make_bfrags(float x, float y, float z,
                                            f16x8* b0, f16x8* b1) {
    const float rn = fmaf(x, x, fmaf(y, y, z * z));
    const _Float16 bhx = (_Float16)x, bhy = (_Float16)y, bhz = (_Float16)z;
    const _Float16 blx = (_Float16)(x - (float)bhx);
    const _Float16 bly = (_Float16)(y - (float)bhy);
    const _Float16 blz = (_Float16)(z - (float)bhz);
    const _Float16 rh = (_Float16)rn, rl = (_Float16)(rn - (float)rh);
    const _Float16 one = (_Float16)1.f;
    *b0 = (f16x8){bhx, bhy, bhz, bhx, bhy, bhz, blx, bly};
    *b1 = (f16x8){blz, blx, bly, blz, one, one, rh, rl};
}

// Stage 1 (fused pack): 32x32x16 MFMA distance tiles, running column-min.
// MFMA issued via inline asm with "=&v" dests -> results are born in arch
// VGPRs (no AGPR round-trip, no v_accvgpr_read per fold operand).
// Hazard: 4 back-to-back MFMAs (>=48cyc separation for tile0 reads) + 4x s_nop 7
// (32cyc) before the asm ends covers the 16-pass-MFMA -> VALU-read wait.
__global__ __launch_bounds__(256) void nn_mfma(
    const float* __restrict__ preds, const float* __restrict__ gts,
    int M, int N, int B, int rsplit, int Qstride, float* __restrict__ part)
{
    const int zc    = blockIdx.z;
    const int dir   = zc / rsplit;       // 0: q=preds ref=gts ; 1: q=gts ref=preds
    const int chunk = zc - dir * rsplit;
    const int b     = blockIdx.y;

    const int Q = dir ? N : M;
    const int R = dir ? M : N;
    const float* __restrict__ qraw = (dir ? gts : preds) + (size_t)b * Q * 3;
    const float* __restrict__ rraw = (dir ? preds : gts) + (size_t)b * R * 3;

    const int q0blk = blockIdx.x * 256;
    if (q0blk >= Q) return;
    const int tid  = threadIdx.x;
    const int lane = tid & 63, w = tid >> 6;
    const int q0   = q0blk + w * 64;            // wave owns queries q0..q0+63
    const int lrow = lane & 31, lh = lane >> 5; // A row / k-half

    float ax = 0.f, ay = 0.f, az = 0.f, bx = 0.f, by = 0.f, bz = 0.f;
    const int qa = q0 + lrow, qb = q0 + 32 + lrow;
    if (qa < Q) { const float* s = qraw + (size_t)qa * 3; ax = s[0]; ay = s[1]; az = s[2]; }
    if (qb < Q) { const float* s = qraw + (size_t)qb * 3; bx = s[0]; by = s[1]; bz = s[2]; }
    const f16x8 af0 = make_afrag(ax, ay, az, lh);
    const f16x8 af1 = make_afrag(bx, by, bz, lh);

    __shared__ f16x8 sB[TILE * 2];

    f32x16 rm0, rm1;
    #pragma unroll
    for (int j = 0; j < 16; ++j) { rm0[j] = INFINITY; rm1[j] = INFINITY; }

    const int tilesTotal = (R + TILE - 1) / TILE;
    const int tpc = (tilesTotal + rsplit - 1) / rsplit;
    const int t0 = chunk * tpc;
    const int t1 = min(tilesTotal, t0 + tpc);

    for (int tt = t0; tt < t1; ++tt) {
        const int s0 = tt * TILE;
        __syncthreads();
        #pragma unroll
        for (int k = 0; k < 4; ++k) {
            const int p  = tid + k * 256;
            const int gi = s0 + p;
            f16x8 b0, b1;
            if (gi < R) {
                const float* s = rraw + (size_t)gi * 3;
                make_bfrags(s[0], s[1], s[2], &b0, &b1);
            } else {
                const _Float16 z0 = (_Float16)0.f, one = (_Float16)1.f;
                const _Float16 big = (_Float16)60000.f;   // pad -> huge dist (finite)
                b0 = (f16x8){z0, z0, z0, z0, z0, z0, z0, z0};
                b1 = (f16x8){z0, z0, z0, z0, one, one, big, z0};
            }
            const int g = p >> 5, sl = p & 31;
            sB[g * 64 + sl]      = b0;
            sB[g * 64 + 32 + sl] = b1;
        }
        __syncthreads();

        // lane reads slot (2tp*64 + lane): contiguous 1KB per wave read
        f16x8 nb0 = sB[lane];
        f16x8 nb1 = sB[64 + lane];
        #pragma unroll 1
        for (int tp = 0; tp < TILE / 64; ++tp) {
            const f16x8 cb0 = nb0, cb1 = nb1;
            if (tp < TILE / 64 - 1) {   // uniform prefetch of next 64-ref pair
                nb0 = sB[(2 * tp + 2) * 64 + lane];
                nb1 = sB[(2 * tp + 3) * 64 + lane];
            }
            f32x16 d00, d01, d10, d11;
            asm volatile(
                "v_mfma_f32_32x32x16_f16 %0, %4, %6, 0\n\t"
                "v_mfma_f32_32x32x16_f16 %1, %4, %7, 0\n\t"
                "v_mfma_f32_32x32x16_f16 %2, %5, %6, 0\n\t"
                "v_mfma_f32_32x32x16_f16 %3, %5, %7, 0\n\t"
                "s_nop 7\n\t"
                "s_nop 7\n\t"
                "s_nop 7\n\t"
                "s_nop 7"
                : "=&v"(d00), "=&v"(d01), "=&v"(d10), "=&v"(d11)
                : "v"(af0), "v"(af1), "v"(cb0), "v"(cb1));
            #pragma unroll
            for (int j = 0; j < 16; ++j) rm0[j] = min3f(d00[j], d01[j], rm0[j]);
            #pragma unroll
            for (int j = 0; j < 16; ++j) rm1[j] = min3f(d10[j], d11[j], rm1[j]);
        }
    }

    // reduce over the 32 ref-columns (xor bits 0-4 stay within the lh group)
    #pragma unroll
    for (int m2 = 1; m2 <= 16; m2 <<= 1) {
        #pragma unroll
        for (int j = 0; j < 16; ++j) {
            rm0[j] = fminf(rm0[j], __shfl_xor(rm0[j], m2, 64));
            rm1[j] = fminf(rm1[j], __shfl_xor(rm1[j], m2, 64));
        }
    }

    // lanes 0 and 32 hold complementary row sets: row = (j&3)+8*(j>>2)+4*lh
    if ((lane & 31) == 0) {
        const size_t pbase = (((size_t)dir * B + b) * rsplit + chunk) * (size_t)Qstride + q0;
        #pragma unroll
        for (int j = 0; j < 16; ++j) {
            const int row = (j & 3) + 8 * (j >> 2) + 4 * lh;
            part[pbase + row]      = rm0[j];
            part[pbase + 32 + row] = rm1[j];
        }
    }
}

// Stage 2: combine rsplit partial mins, Huber, wave reduce, atomicAdd.
__global__ __launch_bounds__(256) void huber_reduce(
    const float* __restrict__ part, const int* __restrict__ cptr,
    int M, int N, int B, int rsplit, int Qstride, float* __restrict__ out)
{
    const int dir = blockIdx.z;
    const int b   = blockIdx.y;
    const int Q   = dir ? N : M;
    const int j   = blockIdx.x * blockDim.x + threadIdx.x;

    float h = 0.f;
    if (j < Q) {
        const size_t base = (((size_t)dir * B + b) * rsplit) * (size_t)Qstride + j;
        float v = part[base];
        #pragma unroll 4
        for (int k = 1; k < rsplit; ++k) v = fminf(v, part[base + (size_t)k * Qstride]);
        const float c = decode_scalar(cptr);
        h = (v < c) ? (0.5f * v * v) : fmaf(c, v, -0.5f * c * c);
    }

    #pragma unroll
    for (int off = 32; off > 0; off >>= 1) h += __shfl_down(h, off, 64);
    if ((threadIdx.x & 63) == 0) atomicAdd(out, h);
}

extern "C" void kernel_launch(void* const* d_in, const int* in_sizes, int n_in,
                              void* d_out, int out_size, void* d_ws, size_t ws_size,
                              hipStream_t stream) {
    const float* preds = (const float*)d_in[0];
    const float* gts   = (const float*)d_in[1];
    const int*   cptr  = (const int*)d_in[2];

    const int B = 4, D = 3;
    const int M = in_sizes[0] / (B * D);
    const int N = in_sizes[1] / (B * D);
    const int Qmax = (M > N) ? M : N;
    const int Qstride = (Qmax + 255) & ~255;
    const int rsplit = 4;

    float* part = (float*)d_ws;   // 2*B*rsplit*Qstride floats (1 MB @ 8192)
    hipMemsetAsync(d_out, 0, (size_t)out_size * sizeof(float), stream);

    dim3 g1(Qstride / 256, B, 2 * rsplit);
    nn_mfma<<<g1, 256, 0, stream>>>(preds, gts, M, N, B, rsplit, Qstride, part);

    dim3 g2((Qmax + 255) / 256, B, 2);
    huber_reduce<<<g2, 256, 0, stream>>>(part, cptr, M, N, B, rsplit, Qstride,
                                         (float*)d_out);
}

// Round 12
// 54.192 us; speedup vs baseline: 1.1415x; 1.0119x over previous
//
#include <hip/hip_runtime.h>
#include <math.h>

typedef _Float16 f16x8 __attribute__((ext_vector_type(8)));
typedef float f32x16 __attribute__((ext_vector_type(16)));

#define TILE 1024  // refs per LDS stage: 1024 * 32B = 32 KB

__device__ __forceinline__ float decode_scalar(const int* p) {
    int i = *p;
    if (i > -16777216 && i < 16777216) return (float)i;
    return __int_as_float(i);
}
__device__ __forceinline__ float min3f(float a, float b, float c) {
    float d;
    asm("v_min3_f32 %0, %1, %2, %3" : "=v"(d) : "v"(a), "v"(b), "v"(c));
    return d;
}

// K=16 encoding, a = -2*pt, hi/lo f16 split, rn = |pt|^2:
//  A (query): [ah3, al3, ah3, al3, qnh, qnl, 1, 1]   (half 0 = k0-7, half 1 = k8-15)
//  B (ref)  : [bh3, bh3, bl3, bl3, 1, 1, rnh, rnl]
//  sum_k A_k B_k = (ah+al)·(bh+bl) + qn + rn = ||q-r||^2 (exact to ~fp32)
__device__ __forceinline__ f16x8 make_afrag(float x, float y, float z, int half) {
    const float rn = fmaf(x, x, fmaf(y, y, z * z));
    const float ax = -2.f * x, ay = -2.f * y, az = -2.f * z;
    const _Float16 ahx = (_Float16)ax, ahy = (_Float16)ay, ahz = (_Float16)az;
    const _Float16 alx = (_Float16)(ax - (float)ahx);
    const _Float16 aly = (_Float16)(ay - (float)ahy);
    const _Float16 alz = (_Float16)(az - (float)ahz);
    const _Float16 rh = (_Float16)rn, rl = (_Float16)(rn - (float)rh);
    const _Float16 one = (_Float16)1.f;
    if (half == 0) return (f16x8){ahx, ahy, ahz, alx, aly, alz, ahx, ahy};
    return (f16x8){ahz, alx, aly, alz, rh, rl, one, one};
}

// Pack each distinct point ONCE into the exact per-tile LDS image:
// tile t (1024 pts, 2048 f16x8): entry = t*2048 + group(p>>5)*64 + (p&31) for
// half0, +32 for half1. Stage-1 staging is then a dumb linear 32KB copy.
__global__ __launch_bounds__(256) void pack_b(
    const float* __restrict__ preds, const float* __restrict__ gts,
    int M, int N, int Mp, int Np, int B,
    f16x8* __restrict__ Bp, f16x8* __restrict__ Bg)
{
    const int which = blockIdx.y;
    const int n  = which ? N : M;
    const int np = which ? Np : Mp;
    const float* __restrict__ src = which ? gts : preds;
    f16x8* __restrict__ out = which ? Bg : Bp;

    const int idx = blockIdx.x * 256 + threadIdx.x;
    if (idx >= B * np) return;
    const int b = idx / np, i = idx - b * np;

    f16x8 b0, b1;
    if (i < n) {
        const float* s = src + ((size_t)b * n + i) * 3;
        const float x = s[0], y = s[1], z = s[2];
        const float rn = fmaf(x, x, fmaf(y, y, z * z));
        const _Float16 bhx = (_Float16)x, bhy = (_Float16)y, bhz = (_Float16)z;
        const _Float16 blx = (_Float16)(x - (float)bhx);
        const _Float16 bly = (_Float16)(y - (float)bhy);
        const _Float16 blz = (_Float16)(z - (float)bhz);
        const _Float16 rh = (_Float16)rn, rl = (_Float16)(rn - (float)rh);
        const _Float16 one = (_Float16)1.f;
        b0 = (f16x8){bhx, bhy, bhz, bhx, bhy, bhz, blx, bly};
        b1 = (f16x8){blz, blx, bly, blz, one, one, rh, rl};
    } else {
        const _Float16 z0 = (_Float16)0.f, one = (_Float16)1.f;
        const _Float16 big = (_Float16)60000.f;   // pad -> huge finite dist
        b0 = (f16x8){z0, z0, z0, z0, z0, z0, z0, z0};
        b1 = (f16x8){z0, z0, z0, z0, one, one, big, z0};
    }
    const size_t e0 = (size_t)b * (np * 2)
                    + (size_t)(i >> 10) * 2048 + ((i >> 5) & 31) * 64 + (i & 31);
    out[e0]      = b0;
    out[e0 + 32] = b1;
}

// Stage 1: 32x32x16 MFMA distance tiles, running column-min. Refs arrive
// pre-packed; staging = linear 32KB copy. MFMA via inline asm ("=&v" dests:
// results born in arch VGPRs, no AGPR round-trip). 4 back-to-back MFMAs +
// 4x s_nop 7 cover the MFMA->VALU-read hazard (validated R11, absmax 0).
__global__ __launch_bounds__(256) void nn_mfma(
    const float* __restrict__ preds, const float* __restrict__ gts,
    const f16x8* __restrict__ Bp, const f16x8* __restrict__ Bg,
    int M, int N, int Mp, int Np, int B, int rsplit, int Qstride,
    float* __restrict__ part)
{
    const int zc    = blockIdx.z;
    const int dir   = zc / rsplit;       // 0: q=preds ref=gts ; 1: q=gts ref=preds
    const int chunk = zc - dir * rsplit;
    const int b     = blockIdx.y;

    const int Q  = dir ? N : M;
    const int Rp = dir ? Mp : Np;
    const float* __restrict__ qraw = (dir ? gts : preds) + (size_t)b * Q * 3;
    const f16x8* __restrict__ gB   = (dir ? Bp : Bg) + (size_t)b * (Rp * 2);

    const int q0blk = blockIdx.x * 256;
    if (q0blk >= Q) return;
    const int tid  = threadIdx.x;
    const int lane = tid & 63, w = tid >> 6;
    const int q0   = q0blk + w * 64;            // wave owns queries q0..q0+63
    const int lrow = lane & 31, lh = lane >> 5; // A row / k-half

    float ax = 0.f, ay = 0.f, az = 0.f, bx = 0.f, by = 0.f, bz = 0.f;
    const int qa = q0 + lrow, qb = q0 + 32 + lrow;
    if (qa < Q) { const float* s = qraw + (size_t)qa * 3; ax = s[0]; ay = s[1]; az = s[2]; }
    if (qb < Q) { const float* s = qraw + (size_t)qb * 3; bx = s[0]; by = s[1]; bz = s[2]; }
    const f16x8 af0 = make_afrag(ax, ay, az, lh);
    const f16x8 af1 = make_afrag(bx, by, bz, lh);

    __shared__ f16x8 sB[TILE * 2];

    f32x16 rm0, rm1;
    #pragma unroll
    for (int j = 0; j < 16; ++j) { rm0[j] = INFINITY; rm1[j] = INFINITY; }

    const int tilesTotal = Rp >> 10;
    const int tpc = (tilesTotal + rsplit - 1) / rsplit;
    const int t0 = chunk * tpc;
    const int t1 = min(tilesTotal, t0 + tpc);

    for (int tt = t0; tt < t1; ++tt) {
        const size_t gbase = (size_t)tt * 2048;
        __syncthreads();
        #pragma unroll
        for (int k = 0; k < 8; ++k) {
            const int s = k * 256 + tid;
            sB[s] = gB[gbase + s];
        }
        __syncthreads();

        // lane reads slot (2tp*64 + lane): contiguous 1KB per wave read
        f16x8 nb0 = sB[lane];
        f16x8 nb1 = sB[64 + lane];
        #pragma unroll 1
        for (int tp = 0; tp < TILE / 64; ++tp) {
            const f16x8 cb0 = nb0, cb1 = nb1;
            if (tp < TILE / 64 - 1) {   // uniform prefetch of next 64-ref pair
                nb0 = sB[(2 * tp + 2) * 64 + lane];
                nb1 = sB[(2 * tp + 3) * 64 + lane];
            }
            f32x16 d00, d01, d10, d11;
            asm volatile(
                "v_mfma_f32_32x32x16_f16 %0, %4, %6, 0\n\t"
                "v_mfma_f32_32x32x16_f16 %1, %4, %7, 0\n\t"
                "v_mfma_f32_32x32x16_f16 %2, %5, %6, 0\n\t"
                "v_mfma_f32_32x32x16_f16 %3, %5, %7, 0\n\t"
                "s_nop 7\n\t"
                "s_nop 7\n\t"
                "s_nop 7\n\t"
                "s_nop 7"
                : "=&v"(d00), "=&v"(d01), "=&v"(d10), "=&v"(d11)
                : "v"(af0), "v"(af1), "v"(cb0), "v"(cb1));
            #pragma unroll
            for (int j = 0; j < 16; ++j) rm0[j] = min3f(d00[j], d01[j], rm0[j]);
            #pragma unroll
            for (int j = 0; j < 16; ++j) rm1[j] = min3f(d10[j], d11[j], rm1[j]);
        }
    }

    // reduce over the 32 ref-columns (xor bits 0-4 stay within the lh group)
    #pragma unroll
    for (int m2 = 1; m2 <= 16; m2 <<= 1) {
        #pragma unroll
        for (int j = 0; j < 16; ++j) {
            rm0[j] = fminf(rm0[j], __shfl_xor(rm0[j], m2, 64));
            rm1[j] = fminf(rm1[j], __shfl_xor(rm1[j], m2, 64));
        }
    }

    // lanes 0 and 32 hold complementary row sets: row = (j&3)+8*(j>>2)+4*lh
    if ((lane & 31) == 0) {
        const size_t pbase = (((size_t)dir * B + b) * rsplit + chunk) * (size_t)Qstride + q0;
        #pragma unroll
        for (int j = 0; j < 16; ++j) {
            const int row = (j & 3) + 8 * (j >> 2) + 4 * lh;
            part[pbase + row]      = rm0[j];
            part[pbase + 32 + row] = rm1[j];
        }
    }
}

// Stage 2: combine rsplit partial mins, Huber, wave reduce, atomicAdd.
__global__ __launch_bounds__(256) void huber_reduce(
    const float* __restrict__ part, const int* __restrict__ cptr,
    int M, int N, int B, int rsplit, int Qstride, float* __restrict__ out)
{
    const int dir = blockIdx.z;
    const int b   = blockIdx.y;
    const int Q   = dir ? N : M;
    const int j   = blockIdx.x * blockDim.x + threadIdx.x;

    float h = 0.f;
    if (j < Q) {
        const size_t base = (((size_t)dir * B + b) * rsplit) * (size_t)Qstride + j;
        float v = part[base];
        #pragma unroll 4
        for (int k = 1; k < rsplit; ++k) v = fminf(v, part[base + (size_t)k * Qstride]);
        const float c = decode_scalar(cptr);
        h = (v < c) ? (0.5f * v * v) : fmaf(c, v, -0.5f * c * c);
    }

    #pragma unroll
    for (int off = 32; off > 0; off >>= 1) h += __shfl_down(h, off, 64);
    if ((threadIdx.x & 63) == 0) atomicAdd(out, h);
}

extern "C" void kernel_launch(void* const* d_in, const int* in_sizes, int n_in,
                              void* d_out, int out_size, void* d_ws, size_t ws_size,
                              hipStream_t stream) {
    const float* preds = (const float*)d_in[0];
    const float* gts   = (const float*)d_in[1];
    const int*   cptr  = (const int*)d_in[2];

    const int B = 4, D = 3;
    const int M = in_sizes[0] / (B * D);
    const int N = in_sizes[1] / (B * D);
    const int Mp = (M + TILE - 1) & ~(TILE - 1);
    const int Np = (N + TILE - 1) & ~(TILE - 1);
    const int Qmax = (M > N) ? M : N;
    const int Qstride = (Qmax + 255) & ~255;
    const int rsplit = 4;

    // ws: Bp (packed preds-as-ref) | Bg (packed gts-as-ref) | part
    f16x8* Bp = (f16x8*)d_ws;
    f16x8* Bg = Bp + (size_t)B * Mp * 2;
    float* part = (float*)(Bg + (size_t)B * Np * 2);

    hipMemsetAsync(d_out, 0, (size_t)out_size * sizeof(float), stream);

    const int npmax = (Mp > Np) ? Mp : Np;
    dim3 g0((B * npmax + 255) / 256, 2, 1);
    pack_b<<<g0, 256, 0, stream>>>(preds, gts, M, N, Mp, Np, B, Bp, Bg);

    dim3 g1(Qstride / 256, B, 2 * rsplit);
    nn_mfma<<<g1, 256, 0, stream>>>(preds, gts, Bp, Bg, M, N, Mp, Np, B,
                                    rsplit, Qstride, part);

    dim3 g2((Qmax + 255) / 256, B, 2);
    huber_reduce<<<g2, 256, 0, stream>>>(part, cptr, M, N, B, rsplit, Qstride,
                                         (float*)d_out);
}

// Round 13
// 41.170 us; speedup vs baseline: 1.5026x; 1.3163x over previous
//
#include <hip/hip_runtime.h>
#include <math.h>

typedef _Float16 f16x8 __attribute__((ext_vector_type(8)));
typedef float f32x16 __attribute__((ext_vector_type(16)));

#define TILE 1024  // refs per LDS stage: 1024 * 32B = 32 KB

__device__ __forceinline__ float decode_scalar(const int* p) {
    int i = *p;
    if (i > -16777216 && i < 16777216) return (float)i;
    return __int_as_float(i);
}
__device__ __forceinline__ float min3f(float a, float b, float c) {
    float d;
    asm("v_min3_f32 %0, %1, %2, %3" : "=v"(d) : "v"(a), "v"(b), "v"(c));
    return d;
}

// K=16 encoding, a = -2*pt, hi/lo f16 split, rn = |pt|^2:
//  A (query): [ah3, al3, ah3, al3, qnh, qnl, 1, 1]   (half 0 = k0-7, half 1 = k8-15)
//  B (ref)  : [bh3, bh3, bl3, bl3, 1, 1, rnh, rnl]
//  sum_k A_k B_k = (ah+al)·(bh+bl) + qn + rn = ||q-r||^2 (exact to ~fp32)
__device__ __forceinline__ f16x8 make_afrag(float x, float y, float z, int half) {
    const float rn = fmaf(x, x, fmaf(y, y, z * z));
    const float ax = -2.f * x, ay = -2.f * y, az = -2.f * z;
    const _Float16 ahx = (_Float16)ax, ahy = (_Float16)ay, ahz = (_Float16)az;
    const _Float16 alx = (_Float16)(ax - (float)ahx);
    const _Float16 aly = (_Float16)(ay - (float)ahy);
    const _Float16 alz = (_Float16)(az - (float)ahz);
    const _Float16 rh = (_Float16)rn, rl = (_Float16)(rn - (float)rh);
    const _Float16 one = (_Float16)1.f;
    if (half == 0) return (f16x8){ahx, ahy, ahz, alx, aly, alz, ahx, ahy};
    return (f16x8){ahz, alx, aly, alz, rh, rl, one, one};
}
__device__ __forceinline__ void make_bfrags(float x, float y, float z,
                                            f16x8* b0, f16x8* b1) {
    const float rn = fmaf(x, x, fmaf(y, y, z * z));
    const _Float16 bhx = (_Float16)x, bhy = (_Float16)y, bhz = (_Float16)z;
    const _Float16 blx = (_Float16)(x - (float)bhx);
    const _Float16 bly = (_Float16)(y - (float)bhy);
    const _Float16 blz = (_Float16)(z - (float)bhz);
    const _Float16 rh = (_Float16)rn, rl = (_Float16)(rn - (float)rh);
    const _Float16 one = (_Float16)1.f;
    *b0 = (f16x8){bhx, bhy, bhz, bhx, bhy, bhz, blx, bly};
    *b1 = (f16x8){blz, blx, bly, blz, one, one, rh, rl};
}

// Stage 1 (fused pack): 32x32x16 MFMA distance tiles, running column-min.
// Conflict-free LDS layout (R10), asm MFMA with VGPR dests (R11, absmax 0).
__global__ __launch_bounds__(256) void nn_mfma(
    const float* __restrict__ preds, const float* __restrict__ gts,
    int M, int N, int B, int rsplit, int Qstride, float* __restrict__ part)
{
    const int zc    = blockIdx.z;
    const int dir   = zc / rsplit;       // 0: q=preds ref=gts ; 1: q=gts ref=preds
    const int chunk = zc - dir * rsplit;
    const int b     = blockIdx.y;

    const int Q = dir ? N : M;
    const int R = dir ? M : N;
    const float* __restrict__ qraw = (dir ? gts : preds) + (size_t)b * Q * 3;
    const float* __restrict__ rraw = (dir ? preds : gts) + (size_t)b * R * 3;

    const int q0blk = blockIdx.x * 256;
    if (q0blk >= Q) return;
    const int tid  = threadIdx.x;
    const int lane = tid & 63, w = tid >> 6;
    const int q0   = q0blk + w * 64;            // wave owns queries q0..q0+63
    const int lrow = lane & 31, lh = lane >> 5; // A row / k-half

    float ax = 0.f, ay = 0.f, az = 0.f, bx = 0.f, by = 0.f, bz = 0.f;
    const int qa = q0 + lrow, qb = q0 + 32 + lrow;
    if (qa < Q) { const float* s = qraw + (size_t)qa * 3; ax = s[0]; ay = s[1]; az = s[2]; }
    if (qb < Q) { const float* s = qraw + (size_t)qb * 3; bx = s[0]; by = s[1]; bz = s[2]; }
    const f16x8 af0 = make_afrag(ax, ay, az, lh);
    const f16x8 af1 = make_afrag(bx, by, bz, lh);

    __shared__ f16x8 sB[TILE * 2];

    f32x16 rm0, rm1;
    #pragma unroll
    for (int j = 0; j < 16; ++j) { rm0[j] = INFINITY; rm1[j] = INFINITY; }

    const int tilesTotal = (R + TILE - 1) / TILE;
    const int tpc = (tilesTotal + rsplit - 1) / rsplit;
    const int t0 = chunk * tpc;
    const int t1 = min(tilesTotal, t0 + tpc);

    for (int tt = t0; tt < t1; ++tt) {
        const int s0 = tt * TILE;
        __syncthreads();
        #pragma unroll
        for (int k = 0; k < 4; ++k) {
            const int p  = tid + k * 256;
            const int gi = s0 + p;
            f16x8 b0, b1;
            if (gi < R) {
                const float* s = rraw + (size_t)gi * 3;
                make_bfrags(s[0], s[1], s[2], &b0, &b1);
            } else {
                const _Float16 z0 = (_Float16)0.f, one = (_Float16)1.f;
                const _Float16 big = (_Float16)60000.f;   // pad -> huge finite dist
                b0 = (f16x8){z0, z0, z0, z0, z0, z0, z0, z0};
                b1 = (f16x8){z0, z0, z0, z0, one, one, big, z0};
            }
            const int g = p >> 5, sl = p & 31;
            sB[g * 64 + sl]      = b0;
            sB[g * 64 + 32 + sl] = b1;
        }
        __syncthreads();

        // lane reads slot (2tp*64 + lane): contiguous 1KB per wave read
        f16x8 nb0 = sB[lane];
        f16x8 nb1 = sB[64 + lane];
        #pragma unroll 1
        for (int tp = 0; tp < TILE / 64; ++tp) {
            const f16x8 cb0 = nb0, cb1 = nb1;
            if (tp < TILE / 64 - 1) {   // uniform prefetch of next 64-ref pair
                nb0 = sB[(2 * tp + 2) * 64 + lane];
                nb1 = sB[(2 * tp + 3) * 64 + lane];
            }
            f32x16 d00, d01, d10, d11;
            asm volatile(
                "v_mfma_f32_32x32x16_f16 %0, %4, %6, 0\n\t"
                "v_mfma_f32_32x32x16_f16 %1, %4, %7, 0\n\t"
                "v_mfma_f32_32x32x16_f16 %2, %5, %6, 0\n\t"
                "v_mfma_f32_32x32x16_f16 %3, %5, %7, 0\n\t"
                "s_nop 7\n\t"
                "s_nop 7\n\t"
                "s_nop 7\n\t"
                "s_nop 7"
                : "=&v"(d00), "=&v"(d01), "=&v"(d10), "=&v"(d11)
                : "v"(af0), "v"(af1), "v"(cb0), "v"(cb1));
            #pragma unroll
            for (int j = 0; j < 16; ++j) rm0[j] = min3f(d00[j], d01[j], rm0[j]);
            #pragma unroll
            for (int j = 0; j < 16; ++j) rm1[j] = min3f(d10[j], d11[j], rm1[j]);
        }
    }

    // reduce over the 32 ref-columns (xor bits 0-4 stay within the lh group)
    #pragma unroll
    for (int m2 = 1; m2 <= 16; m2 <<= 1) {
        #pragma unroll
        for (int j = 0; j < 16; ++j) {
            rm0[j] = fminf(rm0[j], __shfl_xor(rm0[j], m2, 64));
            rm1[j] = fminf(rm1[j], __shfl_xor(rm1[j], m2, 64));
        }
    }

    // lanes 0 and 32 hold complementary row sets: row = (j&3)+8*(j>>2)+4*lh
    if ((lane & 31) == 0) {
        const size_t pbase = (((size_t)dir * B + b) * rsplit + chunk) * (size_t)Qstride + q0;
        #pragma unroll
        for (int j = 0; j < 16; ++j) {
            const int row = (j & 3) + 8 * (j >> 2) + 4 * lh;
            part[pbase + row]      = rm0[j];
            part[pbase + 32 + row] = rm1[j];
        }
    }
}

// Stage 2: combine rsplit partial mins, Huber, wave->block reduce, ONE atomic
// per block (was one per wave to a single address: ~1024 serialized L2 RMWs,
// ~12 us of launch tail).
__global__ __launch_bounds__(1024) void huber_reduce(
    const float* __restrict__ part, const int* __restrict__ cptr,
    int M, int N, int B, int rsplit, int Qstride, float* __restrict__ out)
{
    const int dir = blockIdx.z;
    const int b   = blockIdx.y;
    const int Q   = dir ? N : M;
    const int tid = threadIdx.x;
    const int j   = blockIdx.x * 1024 + tid;

    float h = 0.f;
    if (j < Q) {
        const size_t base = (((size_t)dir * B + b) * rsplit) * (size_t)Qstride + j;
        float v = part[base];
        #pragma unroll 4
        for (int k = 1; k < rsplit; ++k) v = fminf(v, part[base + (size_t)k * Qstride]);
        const float c = decode_scalar(cptr);
        h = (v < c) ? (0.5f * v * v) : fmaf(c, v, -0.5f * c * c);
    }

    #pragma unroll
    for (int off = 32; off > 0; off >>= 1) h += __shfl_down(h, off, 64);

    __shared__ float wsum[16];
    if ((tid & 63) == 0) wsum[tid >> 6] = h;
    __syncthreads();
    if (tid < 64) {
        float t = (tid < 16) ? wsum[tid] : 0.f;
        #pragma unroll
        for (int off = 8; off > 0; off >>= 1) t += __shfl_down(t, off, 64);
        if (tid == 0) atomicAdd(out, t);
    }
}

extern "C" void kernel_launch(void* const* d_in, const int* in_sizes, int n_in,
                              void* d_out, int out_size, void* d_ws, size_t ws_size,
                              hipStream_t stream) {
    const float* preds = (const float*)d_in[0];
    const float* gts   = (const float*)d_in[1];
    const int*   cptr  = (const int*)d_in[2];

    const int B = 4, D = 3;
    const int M = in_sizes[0] / (B * D);
    const int N = in_sizes[1] / (B * D);
    const int Qmax = (M > N) ? M : N;
    const int Qstride = (Qmax + 255) & ~255;
    const int rsplit = 4;

    float* part = (float*)d_ws;   // 2*B*rsplit*Qstride floats (1 MB @ 8192)
    hipMemsetAsync(d_out, 0, (size_t)out_size * sizeof(float), stream);

    dim3 g1(Qstride / 256, B, 2 * rsplit);
    nn_mfma<<<g1, 256, 0, stream>>>(preds, gts, M, N, B, rsplit, Qstride, part);

    dim3 g2((Qmax + 1023) / 1024, B, 2);
    huber_reduce<<<g2, 1024, 0, stream>>>(part, cptr, M, N, B, rsplit, Qstride,
                                          (float*)d_out);
}